// Round 1
// baseline (670.542 us; speedup 1.0000x reference)
//
#include <hip/hip_runtime.h>
#include <hip/hip_bf16.h>

// Problem constants (B*T=8192 tokens, D=2048, E=8, I=1024, top-2)
constexpr int kN = 8192;
constexpr int kD = 2048;
constexpr int kE = 8;
constexpr int kI = 1024;

typedef __bf16 bf16x8 __attribute__((ext_vector_type(8)));
typedef float  f32x4  __attribute__((ext_vector_type(4)));

// ---- workspace layout (bytes). Total ~33.8 MB ----
constexpr size_t OFF_COUNTS = 0;                        // 8 u32
constexpr size_t OFF_PSUM   = 64;                       // 8 f32
constexpr size_t OFF_OFFS   = 128;                      // 8 u32
constexpr size_t OFF_CURSOR = 192;                      // 8 u32
constexpr size_t OFF_TOPE   = 256;                      // N int2
constexpr size_t OFF_TOPW   = OFF_TOPE + (size_t)kN * 8; // N float2
constexpr size_t OFF_TOK    = OFF_TOPW + (size_t)kN * 8; // 2N i32
constexpr size_t OFF_WGT    = OFF_TOK  + (size_t)kN * 8; // 2N f32
constexpr size_t OFF_H      = OFF_WGT  + (size_t)kN * 8; // 2N x kI bf16 = 32MB

// ------------------------------------------------------------------
// Gate: 4 waves/block, 1 token/wave. fp32 logits, softmax, top-2.
// ------------------------------------------------------------------
__global__ __launch_bounds__(256) void gate_kernel(
    const float* __restrict__ x, const float* __restrict__ gw,
    unsigned* __restrict__ counts, float* __restrict__ psum,
    int2* __restrict__ tope, float2* __restrict__ topw)
{
    const int tid  = threadIdx.x;
    const int lane = tid & 63;
    const int wv   = tid >> 6;
    const int t    = blockIdx.x * 4 + wv;

    const float* xr = x + (size_t)t * kD;
    float xv[32];
#pragma unroll
    for (int j = 0; j < 32; ++j) xv[j] = xr[lane + 64 * j];

    float s[8];
#pragma unroll
    for (int e = 0; e < 8; ++e) {
        const float* gr = gw + (size_t)e * kD;
        float a = 0.f;
#pragma unroll
        for (int j = 0; j < 32; ++j) a += xv[j] * gr[lane + 64 * j];
        s[e] = a;
    }
#pragma unroll
    for (int off = 32; off > 0; off >>= 1) {
#pragma unroll
        for (int e = 0; e < 8; ++e) s[e] += __shfl_xor(s[e], off, 64);
    }
    // softmax over 8 (computed redundantly on all lanes; no divergence)
    float mx = s[0];
#pragma unroll
    for (int e = 1; e < 8; ++e) mx = fmaxf(mx, s[e]);
    float p[8]; float sum = 0.f;
#pragma unroll
    for (int e = 0; e < 8; ++e) { p[e] = expf(s[e] - mx); sum += p[e]; }
    float inv = 1.f / sum;
#pragma unroll
    for (int e = 0; e < 8; ++e) p[e] *= inv;

    // top-2 on p (monotone with logits); strict '>' keeps lowest index on ties
    int e0 = 0; float p0 = p[0];
#pragma unroll
    for (int e = 1; e < 8; ++e) if (p[e] > p0) { p0 = p[e]; e0 = e; }
    int e1 = -1; float p1 = -1.f;
#pragma unroll
    for (int e = 0; e < 8; ++e) if (e != e0 && p[e] > p1) { p1 = p[e]; e1 = e; }
    float wn = 1.f / (p0 + p1);

    __shared__ float ps[4][8];
    __shared__ unsigned cnt[8];
    if (tid < 8) cnt[tid] = 0u;
    __syncthreads();
    if (lane == 0) {
#pragma unroll
        for (int e = 0; e < 8; ++e) ps[wv][e] = p[e];
        atomicAdd(&cnt[e0], 1u);
        atomicAdd(&cnt[e1], 1u);
        tope[t] = make_int2(e0, e1);
        topw[t] = make_float2(p0 * wn, p1 * wn);
    }
    __syncthreads();
    if (tid < 8) {
        atomicAdd(&psum[tid], ps[0][tid] + ps[1][tid] + ps[2][tid] + ps[3][tid]);
        if (cnt[tid]) atomicAdd(&counts[tid], cnt[tid]);
    }
}

// ------------------------------------------------------------------
// Scan: offsets/cursors from counts; aux loss -> out[N*D]
// ------------------------------------------------------------------
__global__ void scan_kernel(const unsigned* __restrict__ counts,
                            const float* __restrict__ psum,
                            unsigned* __restrict__ offs,
                            unsigned* __restrict__ cursor,
                            float* __restrict__ out)
{
    if (threadIdx.x == 0) {
        unsigned off = 0;
        float a = 0.f;
        for (int e = 0; e < 8; ++e) {
            offs[e] = off; cursor[e] = off; off += counts[e];
            a += ((float)counts[e] / (float)kN) * (psum[e] / (float)kN);
        }
        out[(size_t)kN * kD] = 0.01f * (float)kE * a;
    }
}

// ------------------------------------------------------------------
// Scatter: counting-sort token assignments by expert
// ------------------------------------------------------------------
__global__ __launch_bounds__(256) void scatter_kernel(
    const int2* __restrict__ tope, const float2* __restrict__ topw,
    unsigned* __restrict__ cursor, int* __restrict__ tok, float* __restrict__ wgt)
{
    int t = blockIdx.x * 256 + threadIdx.x;
    int2 ee = tope[t];
    float2 ww = topw[t];
    unsigned q0 = atomicAdd(&cursor[ee.x], 1u);
    tok[q0] = t; wgt[q0] = ww.x;
    unsigned q1 = atomicAdd(&cursor[ee.y], 1u);
    tok[q1] = t; wgt[q1] = ww.y;
}

// ------------------------------------------------------------------
// C1: per (expert, 128-token tile, 64 h-cols): acc[128][128] where
// cols 0..63 = X·W1^T, 64..127 = X·W3^T. Epilogue: H = silu(a1)*a3 (bf16).
// 4 waves stacked on M (32 rows each) so silu pairing stays in-lane.
// ------------------------------------------------------------------
__global__ __launch_bounds__(256) void ffn_h_kernel(
    const float* __restrict__ x,
    const float* __restrict__ w1, const float* __restrict__ w3,
    const unsigned* __restrict__ counts, const unsigned* __restrict__ offs,
    const int* __restrict__ tok, __bf16* __restrict__ H)
{
    const int e  = blockIdx.z;
    const int mt = blockIdx.y;
    const int ct = blockIdx.x;
    const unsigned n_e = counts[e];
    if ((unsigned)(mt * 128) >= n_e) return;
    const unsigned base = offs[e];

    __shared__ __bf16 a_sm[128][40];   // +8 pad: 80B row stride -> ~2-way banks
    __shared__ __bf16 b_sm[128][40];
    __shared__ int rowtok[128];

    const int tid  = threadIdx.x;
    const int lane = tid & 63;
    const int wv   = tid >> 6;

    if (tid < 128) {
        unsigned r = mt * 128 + (unsigned)tid;
        rowtok[tid] = tok[base + (r < n_e ? r : 0u)];
    }
    __syncthreads();

    const int srow = tid >> 1;           // 0..127
    const int scol = (tid & 1) * 16;     // 0 or 16
    const float* asrc = x + (size_t)rowtok[srow] * kD;
    const float* bsrc = (srow < 64)
        ? (w1 + ((size_t)e * kI + (size_t)ct * 64 + srow) * kD)
        : (w3 + ((size_t)e * kI + (size_t)ct * 64 + (srow - 64)) * kD);

    f32x4 acc[2][8] = {};

    for (int k0 = 0; k0 < kD; k0 += 32) {
        {   // stage A: fp32 -> bf16
            const float* s4 = asrc + k0 + scol;
            float4 f0 = ((const float4*)s4)[0];
            float4 f1 = ((const float4*)s4)[1];
            float4 f2 = ((const float4*)s4)[2];
            float4 f3 = ((const float4*)s4)[3];
            bf16x8 v0, v1;
            v0[0]=(__bf16)f0.x; v0[1]=(__bf16)f0.y; v0[2]=(__bf16)f0.z; v0[3]=(__bf16)f0.w;
            v0[4]=(__bf16)f1.x; v0[5]=(__bf16)f1.y; v0[6]=(__bf16)f1.z; v0[7]=(__bf16)f1.w;
            v1[0]=(__bf16)f2.x; v1[1]=(__bf16)f2.y; v1[2]=(__bf16)f2.z; v1[3]=(__bf16)f2.w;
            v1[4]=(__bf16)f3.x; v1[5]=(__bf16)f3.y; v1[6]=(__bf16)f3.z; v1[7]=(__bf16)f3.w;
            *(bf16x8*)&a_sm[srow][scol]     = v0;
            *(bf16x8*)&a_sm[srow][scol + 8] = v1;
        }
        {   // stage B: rows 0..63 = W1 rows (h cols), 64..127 = W3 rows
            const float* s4 = bsrc + k0 + scol;
            float4 f0 = ((const float4*)s4)[0];
            float4 f1 = ((const float4*)s4)[1];
            float4 f2 = ((const float4*)s4)[2];
            float4 f3 = ((const float4*)s4)[3];
            bf16x8 v0, v1;
            v0[0]=(__bf16)f0.x; v0[1]=(__bf16)f0.y; v0[2]=(__bf16)f0.z; v0[3]=(__bf16)f0.w;
            v0[4]=(__bf16)f1.x; v0[5]=(__bf16)f1.y; v0[6]=(__bf16)f1.z; v0[7]=(__bf16)f1.w;
            v1[0]=(__bf16)f2.x; v1[1]=(__bf16)f2.y; v1[2]=(__bf16)f2.z; v1[3]=(__bf16)f2.w;
            v1[4]=(__bf16)f3.x; v1[5]=(__bf16)f3.y; v1[6]=(__bf16)f3.z; v1[7]=(__bf16)f3.w;
            *(bf16x8*)&b_sm[srow][scol]     = v0;
            *(bf16x8*)&b_sm[srow][scol + 8] = v1;
        }
        __syncthreads();

        bf16x8 af0 = *(const bf16x8*)&a_sm[wv*32      + (lane & 15)][(lane >> 4) * 8];
        bf16x8 af1 = *(const bf16x8*)&a_sm[wv*32 + 16 + (lane & 15)][(lane >> 4) * 8];
#pragma unroll
        for (int n = 0; n < 8; ++n) {
            bf16x8 bf = *(const bf16x8*)&b_sm[n*16 + (lane & 15)][(lane >> 4) * 8];
            acc[0][n] = __builtin_amdgcn_mfma_f32_16x16x32_bf16(af0, bf, acc[0][n], 0, 0, 0);
            acc[1][n] = __builtin_amdgcn_mfma_f32_16x16x32_bf16(af1, bf, acc[1][n], 0, 0, 0);
        }
        __syncthreads();
    }

    // epilogue: h = silu(a1) * a3 ; C/D layout: col=lane&15, row=(lane>>4)*4+j
    const int c0 = lane & 15;
    const int r0 = (lane >> 4) * 4;
#pragma unroll
    for (int m = 0; m < 2; ++m) {
#pragma unroll
        for (int n = 0; n < 4; ++n) {
#pragma unroll
            for (int j = 0; j < 4; ++j) {
                unsigned grow = (unsigned)(mt*128 + wv*32 + m*16 + r0 + j);
                if (grow < n_e) {
                    float a1 = acc[m][n][j];
                    float a3 = acc[m][n + 4][j];
                    float h = a1 / (1.f + __expf(-a1)) * a3;
                    H[(size_t)(base + grow) * kI + (size_t)ct*64 + n*16 + c0] = (__bf16)h;
                }
            }
        }
    }
}

// ------------------------------------------------------------------
// C2: per (expert, 128-slot tile, 64 d-cols): out += w_tok * H·W2^T
// ------------------------------------------------------------------
__global__ __launch_bounds__(256) void ffn_out_kernel(
    const __bf16* __restrict__ H, const float* __restrict__ w2,
    const unsigned* __restrict__ counts, const unsigned* __restrict__ offs,
    const int* __restrict__ tok, const float* __restrict__ wgt,
    float* __restrict__ out)
{
    const int e  = blockIdx.z;
    const int mt = blockIdx.y;
    const int ct = blockIdx.x;
    const unsigned n_e = counts[e];
    if ((unsigned)(mt * 128) >= n_e) return;
    const unsigned base = offs[e];

    __shared__ __bf16 a_sm[128][40];
    __shared__ __bf16 b_sm[64][40];

    const int tid  = threadIdx.x;
    const int lane = tid & 63;
    const int wv   = tid >> 6;

    const int arow = tid >> 1;          // 0..127
    const int acol = (tid & 1) * 16;    // 0 or 16
    unsigned argrow = (unsigned)(mt*128 + arow);
    unsigned aslot  = base + (argrow < n_e ? argrow : 0u);
    const __bf16* asrc = H + (size_t)aslot * kI;

    const int brow = tid >> 2;          // 0..63
    const int bcol = (tid & 3) * 8;     // 0,8,16,24
    const float* bsrc = w2 + ((size_t)e * kD + (size_t)ct * 64 + brow) * kI;

    f32x4 acc[2][4] = {};

    for (int k0 = 0; k0 < kI; k0 += 32) {
        {   // stage A: H already bf16, straight copy
            const bf16x8* s8 = (const bf16x8*)(asrc + k0 + acol);
            bf16x8 h0 = s8[0], h1 = s8[1];
            *(bf16x8*)&a_sm[arow][acol]     = h0;
            *(bf16x8*)&a_sm[arow][acol + 8] = h1;
        }
        {   // stage B: w2 fp32 -> bf16
            const float4* s4 = (const float4*)(bsrc + k0 + bcol);
            float4 f0 = s4[0], f1 = s4[1];
            bf16x8 v;
            v[0]=(__bf16)f0.x; v[1]=(__bf16)f0.y; v[2]=(__bf16)f0.z; v[3]=(__bf16)f0.w;
            v[4]=(__bf16)f1.x; v[5]=(__bf16)f1.y; v[6]=(__bf16)f1.z; v[7]=(__bf16)f1.w;
            *(bf16x8*)&b_sm[brow][bcol] = v;
        }
        __syncthreads();

        bf16x8 af0 = *(const bf16x8*)&a_sm[wv*32      + (lane & 15)][(lane >> 4) * 8];
        bf16x8 af1 = *(const bf16x8*)&a_sm[wv*32 + 16 + (lane & 15)][(lane >> 4) * 8];
#pragma unroll
        for (int n = 0; n < 4; ++n) {
            bf16x8 bf = *(const bf16x8*)&b_sm[n*16 + (lane & 15)][(lane >> 4) * 8];
            acc[0][n] = __builtin_amdgcn_mfma_f32_16x16x32_bf16(af0, bf, acc[0][n], 0, 0, 0);
            acc[1][n] = __builtin_amdgcn_mfma_f32_16x16x32_bf16(af1, bf, acc[1][n], 0, 0, 0);
        }
        __syncthreads();
    }

    const int c0 = lane & 15;
    const int r0 = (lane >> 4) * 4;
#pragma unroll
    for (int m = 0; m < 2; ++m) {
#pragma unroll
        for (int j = 0; j < 4; ++j) {
            unsigned grow = (unsigned)(mt*128 + wv*32 + m*16 + r0 + j);
            if (grow < n_e) {
                unsigned slot = base + grow;
                int   t = tok[slot];
                float w = wgt[slot];
                float* orow = out + (size_t)t * kD + (size_t)ct * 64;
#pragma unroll
                for (int n = 0; n < 4; ++n)
                    atomicAdd(&orow[n*16 + c0], w * acc[m][n][j]);
            }
        }
    }
}

// ------------------------------------------------------------------
extern "C" void kernel_launch(void* const* d_in, const int* in_sizes, int n_in,
                              void* d_out, int out_size, void* d_ws, size_t ws_size,
                              hipStream_t stream)
{
    const float* x  = (const float*)d_in[0];
    const float* gw = (const float*)d_in[1];
    const float* w1 = (const float*)d_in[2];
    const float* w3 = (const float*)d_in[3];
    const float* w2 = (const float*)d_in[4];
    float* out = (float*)d_out;
    char*  ws  = (char*)d_ws;

    unsigned* counts = (unsigned*)(ws + OFF_COUNTS);
    float*    psum   = (float*)(ws + OFF_PSUM);
    unsigned* offs   = (unsigned*)(ws + OFF_OFFS);
    unsigned* cursor = (unsigned*)(ws + OFF_CURSOR);
    int2*     tope   = (int2*)(ws + OFF_TOPE);
    float2*   topw   = (float2*)(ws + OFF_TOPW);
    int*      tok    = (int*)(ws + OFF_TOK);
    float*    wgt    = (float*)(ws + OFF_WGT);
    __bf16*   H      = (__bf16*)(ws + OFF_H);

    // out is accumulated via atomics; aux written by scan_kernel
    hipMemsetAsync(d_out, 0, (size_t)out_size * sizeof(float), stream);
    hipMemsetAsync(d_ws, 0, 256, stream);

    gate_kernel<<<kN / 4, 256, 0, stream>>>(x, gw, counts, psum, tope, topw);
    scan_kernel<<<1, 64, 0, stream>>>(counts, psum, offs, cursor, out);
    scatter_kernel<<<kN / 256, 256, 0, stream>>>(tope, topw, cursor, tok, wgt);
    ffn_h_kernel<<<dim3(kI / 64, kN / 128, kE), 256, 0, stream>>>(
        x, w1, w3, counts, offs, tok, H);
    ffn_out_kernel<<<dim3(kD / 64, kN / 128, kE), 256, 0, stream>>>(
        H, w2, counts, offs, tok, wgt, out);
}

// Round 2
// 581.564 us; speedup vs baseline: 1.1530x; 1.1530x over previous
//
#include <hip/hip_runtime.h>
#include <hip/hip_bf16.h>

// Problem constants (B*T=8192 tokens, D=2048, E=8, I=1024, top-2)
constexpr int kN = 8192;
constexpr int kD = 2048;
constexpr int kE = 8;
constexpr int kI = 1024;

typedef __bf16 bf16x8 __attribute__((ext_vector_type(8)));
typedef float  f32x4  __attribute__((ext_vector_type(4)));

// ---- workspace layout (bytes). Total ~160.3 MiB ----
constexpr size_t OFF_COUNTS = 0;                          // 8 u32
constexpr size_t OFF_PSUM   = 64;                         // 8 f32
constexpr size_t OFF_OFFS   = 128;                        // 8 u32
constexpr size_t OFF_CURSOR = 192;                        // 8 u32
constexpr size_t OFF_TOPE   = 256;                        // N int2
constexpr size_t OFF_TOPW   = OFF_TOPE + (size_t)kN * 8;  // N float2
constexpr size_t OFF_TOK    = OFF_TOPW + (size_t)kN * 8;  // 2N i32
constexpr size_t OFF_WGT    = OFF_TOK  + (size_t)kN * 8;  // 2N f32
constexpr size_t OFF_XB     = OFF_WGT  + (size_t)kN * 8;            // N*D bf16   (32MB)
constexpr size_t OFF_W1B    = OFF_XB  + (size_t)kN * kD * 2;        // E*I*D bf16 (32MB)
constexpr size_t OFF_W3B    = OFF_W1B + (size_t)kE * kI * kD * 2;   // E*I*D bf16 (32MB)
constexpr size_t OFF_W2B    = OFF_W3B + (size_t)kE * kI * kD * 2;   // E*D*I bf16 (32MB)
constexpr size_t OFF_H      = OFF_W2B + (size_t)kE * kD * kI * 2;   // 2N*I bf16  (32MB)

// async global->LDS, 16B per lane. LDS dest must be wave-uniform (HW: base + lane*16).
typedef __attribute__((address_space(1))) const unsigned GU;
typedef __attribute__((address_space(3))) unsigned LU;
__device__ __forceinline__ void gload16(const void* g, void* l) {
    __builtin_amdgcn_global_load_lds((GU*)g, (LU*)l, 16, 0, 0);
}

// ------------------------------------------------------------------
// fp32 -> bf16 bulk convert (vectorized, grid-stride)
// ------------------------------------------------------------------
__global__ __launch_bounds__(256) void convert_kernel(
    const float* __restrict__ src, __bf16* __restrict__ dst, int n8)
{
    int i = blockIdx.x * 256 + threadIdx.x;
    const int stride = gridDim.x * 256;
    for (; i < n8; i += stride) {
        const float4* s = (const float4*)(src + (size_t)i * 8);
        float4 f0 = s[0], f1 = s[1];
        bf16x8 v;
        v[0]=(__bf16)f0.x; v[1]=(__bf16)f0.y; v[2]=(__bf16)f0.z; v[3]=(__bf16)f0.w;
        v[4]=(__bf16)f1.x; v[5]=(__bf16)f1.y; v[6]=(__bf16)f1.z; v[7]=(__bf16)f1.w;
        *(bf16x8*)(dst + (size_t)i * 8) = v;
    }
}

// ------------------------------------------------------------------
// Gate: 4 waves/block, 1 token/wave. fp32 logits, softmax, top-2.
// ------------------------------------------------------------------
__global__ __launch_bounds__(256) void gate_kernel(
    const float* __restrict__ x, const float* __restrict__ gw,
    unsigned* __restrict__ counts, float* __restrict__ psum,
    int2* __restrict__ tope, float2* __restrict__ topw)
{
    const int tid  = threadIdx.x;
    const int lane = tid & 63;
    const int wv   = tid >> 6;
    const int t    = blockIdx.x * 4 + wv;

    const float* xr = x + (size_t)t * kD;
    float xv[32];
#pragma unroll
    for (int j = 0; j < 32; ++j) xv[j] = xr[lane + 64 * j];

    float s[8];
#pragma unroll
    for (int e = 0; e < 8; ++e) {
        const float* gr = gw + (size_t)e * kD;
        float a = 0.f;
#pragma unroll
        for (int j = 0; j < 32; ++j) a += xv[j] * gr[lane + 64 * j];
        s[e] = a;
    }
#pragma unroll
    for (int off = 32; off > 0; off >>= 1) {
#pragma unroll
        for (int e = 0; e < 8; ++e) s[e] += __shfl_xor(s[e], off, 64);
    }
    float mx = s[0];
#pragma unroll
    for (int e = 1; e < 8; ++e) mx = fmaxf(mx, s[e]);
    float p[8]; float sum = 0.f;
#pragma unroll
    for (int e = 0; e < 8; ++e) { p[e] = expf(s[e] - mx); sum += p[e]; }
    float inv = 1.f / sum;
#pragma unroll
    for (int e = 0; e < 8; ++e) p[e] *= inv;

    // top-2 (strict '>' keeps lowest index on ties, matching lax.top_k)
    int e0 = 0; float p0 = p[0];
#pragma unroll
    for (int e = 1; e < 8; ++e) if (p[e] > p0) { p0 = p[e]; e0 = e; }
    int e1 = -1; float p1 = -1.f;
#pragma unroll
    for (int e = 0; e < 8; ++e) if (e != e0 && p[e] > p1) { p1 = p[e]; e1 = e; }
    float wn = 1.f / (p0 + p1);

    __shared__ float ps[4][8];
    __shared__ unsigned cnt[8];
    if (tid < 8) cnt[tid] = 0u;
    __syncthreads();
    if (lane == 0) {
#pragma unroll
        for (int e = 0; e < 8; ++e) ps[wv][e] = p[e];
        atomicAdd(&cnt[e0], 1u);
        atomicAdd(&cnt[e1], 1u);
        tope[t] = make_int2(e0, e1);
        topw[t] = make_float2(p0 * wn, p1 * wn);
    }
    __syncthreads();
    if (tid < 8) {
        atomicAdd(&psum[tid], ps[0][tid] + ps[1][tid] + ps[2][tid] + ps[3][tid]);
        if (cnt[tid]) atomicAdd(&counts[tid], cnt[tid]);
    }
}

// ------------------------------------------------------------------
// Scan: offsets/cursors from counts; aux loss -> out[N*D]
// ------------------------------------------------------------------
__global__ void scan_kernel(const unsigned* __restrict__ counts,
                            const float* __restrict__ psum,
                            unsigned* __restrict__ offs,
                            unsigned* __restrict__ cursor,
                            float* __restrict__ out)
{
    if (threadIdx.x == 0) {
        unsigned off = 0;
        float a = 0.f;
        for (int e = 0; e < 8; ++e) {
            offs[e] = off; cursor[e] = off; off += counts[e];
            a += ((float)counts[e] / (float)kN) * (psum[e] / (float)kN);
        }
        out[(size_t)kN * kD] = 0.01f * (float)kE * a;
    }
}

// ------------------------------------------------------------------
// Scatter: counting-sort token assignments by expert
// ------------------------------------------------------------------
__global__ __launch_bounds__(256) void scatter_kernel(
    const int2* __restrict__ tope, const float2* __restrict__ topw,
    unsigned* __restrict__ cursor, int* __restrict__ tok, float* __restrict__ wgt)
{
    int t = blockIdx.x * 256 + threadIdx.x;
    int2 ee = tope[t];
    float2 ww = topw[t];
    unsigned q0 = atomicAdd(&cursor[ee.x], 1u);
    tok[q0] = t; wgt[q0] = ww.x;
    unsigned q1 = atomicAdd(&cursor[ee.y], 1u);
    tok[q1] = t; wgt[q1] = ww.y;
}

// ------------------------------------------------------------------
// C1 (m97 structure): 128x128 tile, BK=64, 4 waves in 2x2, 64x64/wave.
// Output cols = 64 h-values; B rows ordered [w1 h0-31 | w3 h0-31 | w1 h32-63 | w3 h32-63]
// so a1=acc[m][n], a3=acc[m][n+2] are in-lane for SwiGLU.
// LDS [128][64] bf16, XOR-swizzled: 16B slot p holds logical slot p^(row&7).
// Stage side pre-swizzles the GLOBAL source address (rule #21).
// ------------------------------------------------------------------
__global__ __launch_bounds__(256) void ffn_h_kernel(
    const __bf16* __restrict__ xb,
    const __bf16* __restrict__ w1b, const __bf16* __restrict__ w3b,
    const unsigned* __restrict__ counts, const unsigned* __restrict__ offs,
    const int* __restrict__ tok, __bf16* __restrict__ H)
{
    const int e  = blockIdx.z;
    const int mt = blockIdx.y;
    const int ct = blockIdx.x;
    const unsigned n_e = counts[e];
    if ((unsigned)(mt * 128) >= n_e) return;
    const unsigned base = offs[e];

    __shared__ __bf16 As[128][64];
    __shared__ __bf16 Bs[128][64];
    __shared__ int rowtok[128];

    const int tid  = threadIdx.x;
    const int lane = tid & 63;
    const int wv   = tid >> 6;
    const int wr   = wv >> 1, wc = wv & 1;

    if (tid < 128) {
        unsigned r = (unsigned)(mt * 128 + tid);
        rowtok[tid] = tok[base + (r < n_e ? r : 0u)];
    }
    __syncthreads();

    // hoisted per-lane staging pointers: 4 gload16 calls each for A and B
    const __bf16* aptr[4];
    const __bf16* bptr[4];
    __bf16* alds[4];
    __bf16* blds[4];
#pragma unroll
    for (int j = 0; j < 4; ++j) {
        const int r = wv * 32 + j * 8 + (lane >> 3);
        const int c = (((lane & 7) ^ (r & 7)) << 3);   // pre-swizzled source col
        aptr[j] = xb + (size_t)rowtok[r] * kD + c;
        alds[j] = &As[wv * 32 + j * 8][0];
        const int rr = r & 63;
        const int h  = ct * 64 + ((r >> 6) << 5) + (rr & 31);
        const __bf16* wsrc = (rr < 32) ? w1b : w3b;
        bptr[j] = wsrc + ((size_t)e * kI + h) * kD + c;
        blds[j] = &Bs[wv * 32 + j * 8][0];
    }

    f32x4 acc[4][4] = {};

    for (int k0 = 0; k0 < kD; k0 += 64) {
#pragma unroll
        for (int j = 0; j < 4; ++j) {
            gload16(aptr[j], alds[j]);
            gload16(bptr[j], blds[j]);
            aptr[j] += 64; bptr[j] += 64;
        }
        __syncthreads();

#pragma unroll
        for (int kk = 0; kk < 2; ++kk) {
            bf16x8 af[4];
#pragma unroll
            for (int m = 0; m < 4; ++m) {
                const int r = wr * 64 + m * 16 + (lane & 15);
                const int slot = (kk * 4 + (lane >> 4)) ^ (r & 7);
                af[m] = *(const bf16x8*)&As[r][slot << 3];
            }
#pragma unroll
            for (int n = 0; n < 4; ++n) {
                const int r = wc * 64 + n * 16 + (lane & 15);
                const int slot = (kk * 4 + (lane >> 4)) ^ (r & 7);
                bf16x8 bf = *(const bf16x8*)&Bs[r][slot << 3];
#pragma unroll
                for (int m = 0; m < 4; ++m)
                    acc[m][n] = __builtin_amdgcn_mfma_f32_16x16x32_bf16(af[m], bf, acc[m][n], 0, 0, 0);
            }
        }
        __syncthreads();
    }

    // epilogue: h = silu(a1)*a3; C/D: col=lane&15, row=(lane>>4)*4+j
    const int c0 = lane & 15;
    const int r0 = (lane >> 4) * 4;
    const int hbase = ct * 64 + wc * 32;
#pragma unroll
    for (int m = 0; m < 4; ++m) {
        const unsigned growb = (unsigned)(mt * 128 + wr * 64 + m * 16 + r0);
#pragma unroll
        for (int jj = 0; jj < 4; ++jj) {
            const unsigned grow = growb + jj;
            if (grow < n_e) {
                const size_t rowoff = (size_t)(base + grow) * kI;
#pragma unroll
                for (int n = 0; n < 2; ++n) {
                    float a1 = acc[m][n][jj];
                    float a3 = acc[m][n + 2][jj];
                    float h = a1 / (1.f + __expf(-a1)) * a3;
                    H[rowoff + hbase + n * 16 + c0] = (__bf16)h;
                }
            }
        }
    }
}

// ------------------------------------------------------------------
// C2 (m97 structure): 128 slots x 128 d-cols, BK=64, K=I=1024.
// out += wgt * H·W2^T via fp32 atomicAdd (each token gets exactly 2 adds).
// ------------------------------------------------------------------
__global__ __launch_bounds__(256) void ffn_out_kernel(
    const __bf16* __restrict__ H, const __bf16* __restrict__ w2b,
    const unsigned* __restrict__ counts, const unsigned* __restrict__ offs,
    const int* __restrict__ tok, const float* __restrict__ wgt,
    float* __restrict__ out)
{
    const int e  = blockIdx.z;
    const int mt = blockIdx.y;
    const int ct = blockIdx.x;
    const unsigned n_e = counts[e];
    if ((unsigned)(mt * 128) >= n_e) return;
    const unsigned base = offs[e];

    __shared__ __bf16 As[128][64];
    __shared__ __bf16 Bs[128][64];

    const int tid  = threadIdx.x;
    const int lane = tid & 63;
    const int wv   = tid >> 6;
    const int wr   = wv >> 1, wc = wv & 1;

    const __bf16* aptr[4];
    const __bf16* bptr[4];
    __bf16* alds[4];
    __bf16* blds[4];
#pragma unroll
    for (int j = 0; j < 4; ++j) {
        const int r = wv * 32 + j * 8 + (lane >> 3);
        const int c = (((lane & 7) ^ (r & 7)) << 3);
        const unsigned grow = (unsigned)(mt * 128 + r);
        const unsigned slot = base + (grow < n_e ? grow : 0u);
        aptr[j] = H + (size_t)slot * kI + c;
        alds[j] = &As[wv * 32 + j * 8][0];
        bptr[j] = w2b + ((size_t)e * kD + ct * 128 + r) * kI + c;
        blds[j] = &Bs[wv * 32 + j * 8][0];
    }

    f32x4 acc[4][4] = {};

    for (int k0 = 0; k0 < kI; k0 += 64) {
#pragma unroll
        for (int j = 0; j < 4; ++j) {
            gload16(aptr[j], alds[j]);
            gload16(bptr[j], blds[j]);
            aptr[j] += 64; bptr[j] += 64;
        }
        __syncthreads();

#pragma unroll
        for (int kk = 0; kk < 2; ++kk) {
            bf16x8 af[4];
#pragma unroll
            for (int m = 0; m < 4; ++m) {
                const int r = wr * 64 + m * 16 + (lane & 15);
                const int slot = (kk * 4 + (lane >> 4)) ^ (r & 7);
                af[m] = *(const bf16x8*)&As[r][slot << 3];
            }
#pragma unroll
            for (int n = 0; n < 4; ++n) {
                const int r = wc * 64 + n * 16 + (lane & 15);
                const int slot = (kk * 4 + (lane >> 4)) ^ (r & 7);
                bf16x8 bf = *(const bf16x8*)&Bs[r][slot << 3];
#pragma unroll
                for (int m = 0; m < 4; ++m)
                    acc[m][n] = __builtin_amdgcn_mfma_f32_16x16x32_bf16(af[m], bf, acc[m][n], 0, 0, 0);
            }
        }
        __syncthreads();
    }

    const int c0 = lane & 15;
    const int r0 = (lane >> 4) * 4;
#pragma unroll
    for (int m = 0; m < 4; ++m) {
#pragma unroll
        for (int jj = 0; jj < 4; ++jj) {
            const unsigned grow = (unsigned)(mt * 128 + wr * 64 + m * 16 + r0 + jj);
            if (grow < n_e) {
                const unsigned slot = base + grow;
                const int   t = tok[slot];
                const float w = wgt[slot];
                float* orow = out + (size_t)t * kD + ct * 128 + wc * 64;
#pragma unroll
                for (int n = 0; n < 4; ++n)
                    atomicAdd(&orow[n * 16 + c0], w * acc[m][n][jj]);
            }
        }
    }
}

// ------------------------------------------------------------------
extern "C" void kernel_launch(void* const* d_in, const int* in_sizes, int n_in,
                              void* d_out, int out_size, void* d_ws, size_t ws_size,
                              hipStream_t stream)
{
    const float* x  = (const float*)d_in[0];
    const float* gw = (const float*)d_in[1];
    const float* w1 = (const float*)d_in[2];
    const float* w3 = (const float*)d_in[3];
    const float* w2 = (const float*)d_in[4];
    float* out = (float*)d_out;
    char*  ws  = (char*)d_ws;

    unsigned* counts = (unsigned*)(ws + OFF_COUNTS);
    float*    psum   = (float*)(ws + OFF_PSUM);
    unsigned* offs   = (unsigned*)(ws + OFF_OFFS);
    unsigned* cursor = (unsigned*)(ws + OFF_CURSOR);
    int2*     tope   = (int2*)(ws + OFF_TOPE);
    float2*   topw   = (float2*)(ws + OFF_TOPW);
    int*      tok    = (int*)(ws + OFF_TOK);
    float*    wgt    = (float*)(ws + OFF_WGT);
    __bf16*   xb     = (__bf16*)(ws + OFF_XB);
    __bf16*   w1b    = (__bf16*)(ws + OFF_W1B);
    __bf16*   w3b    = (__bf16*)(ws + OFF_W3B);
    __bf16*   w2b    = (__bf16*)(ws + OFF_W2B);
    __bf16*   H      = (__bf16*)(ws + OFF_H);

    hipMemsetAsync(d_out, 0, (size_t)out_size * sizeof(float), stream);
    hipMemsetAsync(d_ws, 0, 256, stream);

    gate_kernel<<<kN / 4, 256, 0, stream>>>(x, gw, counts, psum, tope, topw);
    scan_kernel<<<1, 64, 0, stream>>>(counts, psum, offs, cursor, out);
    scatter_kernel<<<kN / 256, 256, 0, stream>>>(tope, topw, cursor, tok, wgt);

    const int n8w = kE * kI * kD / 8;           // 2.1M vec8 per weight tensor
    convert_kernel<<<2048, 256, 0, stream>>>(x,  xb,  kN * kD / 8);
    convert_kernel<<<2048, 256, 0, stream>>>(w1, w1b, n8w);
    convert_kernel<<<2048, 256, 0, stream>>>(w3, w3b, n8w);
    convert_kernel<<<2048, 256, 0, stream>>>(w2, w2b, n8w);

    ffn_h_kernel<<<dim3(kI / 64, 2 * kN / 128, kE), 256, 0, stream>>>(
        xb, w1b, w3b, counts, offs, tok, H);
    ffn_out_kernel<<<dim3(kD / 128, 2 * kN / 128, kE), 256, 0, stream>>>(
        H, w2b, counts, offs, tok, wgt, out);
}